// Round 16
// baseline (32.789 us; speedup 1.0000x reference)
//
#include <hip/hip_runtime.h>
#include <hip/hip_bf16.h>
#include <stdint.h>

// VoxelSetAbstraction: ball query + group + shared MLP (2 layers) + maxpool.
// Round 16: R15 + early k=1 fragment gather. Both k-groups' feats gathers
// issue back-to-back right after the query phase (records already in regs),
// so the k=1 gather latency hides under the k=0 gather/barrier instead of
// sitting exposed after the wlds restage.
//   K1 prep_bin: blocks 0-1 pack scaled weights; blocks 2..B+1 LDS-histogram
//      binning (no global zeroing, no global atomics).
//   K2 query_mlp: per-wave query + MFMA MLP (A-frags in block LDS).
//
// Fixed instance: RADII=(0.8,1.6), NSAMPLES=(16,32), IN_C=64, cin=67,
// BOX=(40,40,4), B=2, N=16384, M=4096.
// Radius constants: reference computes r*r in f64 then weak-casts to f32:
// f32(0.64) / f32(2.56) == literals 0.64f / 2.56f (NOT 0.8f*0.8f, 1 ulp off).

#define NS0 16
#define NS1 32
#define NXC 25
#define NYC 25
#define NZC 3
#define CPB (NXC * NYC * NZC)   // 1875 cells per batch
#define CINV 0.625f             // 1/1.6, exact in fp32
#define CSZ 1.6f
#define CAP 48                  // max points/cell (Poisson lambda~5.2 -> safe)

typedef _Float16 half8 __attribute__((ext_vector_type(8)));
typedef float f32x4 __attribute__((ext_vector_type(4)));

static __device__ __forceinline__ half8 cvt8(float4 a, float4 b) {
    half8 r;
    r[0] = (_Float16)a.x; r[1] = (_Float16)a.y; r[2] = (_Float16)a.z; r[3] = (_Float16)a.w;
    r[4] = (_Float16)b.x; r[5] = (_Float16)b.y; r[6] = (_Float16)b.z; r[7] = (_Float16)b.w;
    return r;
}
static __device__ __forceinline__ uint32_t pk2(float x, float y) {
    const _Float16 a = (_Float16)x, c = (_Float16)y;
    return (uint32_t)__builtin_bit_cast(uint16_t, a) |
           ((uint32_t)__builtin_bit_cast(uint16_t, c) << 16);
}

// ---------------- K1: pack weights (blocks 0-1) || bin (blocks 2..B+1) -----
__global__ __launch_bounds__(1024) void prep_bin(
    const float* __restrict__ xyz, const int* __restrict__ xcnt, int N,
    const float* __restrict__ w00, const float* __restrict__ g00, const float* __restrict__ b00,
    const float* __restrict__ w01, const float* __restrict__ g01, const float* __restrict__ b01,
    const float* __restrict__ w10, const float* __restrict__ g10, const float* __restrict__ b10,
    const float* __restrict__ w11, const float* __restrict__ g11, const float* __restrict__ b11,
    float* __restrict__ wpk, int* __restrict__ cell_cnt,
    float4* __restrict__ binned4)
{
    if (blockIdx.x < 2) {
        const int k = blockIdx.x;
        const int tid = threadIdx.x;
        if (tid >= 256) return;
        const int lane = tid & 63, t = tid >> 6;
        const int p = lane & 15, h = lane >> 4;
        const float* W1 = k ? w10 : w00; const float* G1 = k ? g10 : g00; const float* B1 = k ? b10 : b00;
        const float* W2 = k ? w11 : w01; const float* G2 = k ? g11 : g01; const float* B2 = k ? b11 : b01;
        const float inv = 1.0f / sqrtf(1.0f + 1e-3f);

        uint32_t* outw = (uint32_t*)wpk + (size_t)k * 6144;
        const int m = 16 * t + p;
        const float sc1 = G1[m] * inv;
        #pragma unroll
        for (int s = 0; s < 3; ++s) {
            #pragma unroll
            for (int r = 0; r < 4; ++r) {
                uint32_t u = 0;
                #pragma unroll
                for (int e = 0; e < 2; ++e) {
                    const int cpad = 32 * s + 8 * h + 2 * r + e;
                    float val = 0.f;
                    if (cpad < 64)       val = W1[m * 67 + 3 + cpad] * sc1;
                    else if (cpad < 67)  val = W1[m * 67 + (cpad - 64)] * sc1;
                    else if (cpad == 67) val = B1[m];
                    const _Float16 hv = (_Float16)val;
                    u |= ((uint32_t)__builtin_bit_cast(uint16_t, hv)) << (16 * e);
                }
                outw[((t * 3 + s) * 64 + lane) * 4 + r] = u;
            }
        }
        const float sc2 = G2[m] * inv;
        uint32_t* outw2 = outw + 3072;
        #pragma unroll
        for (int s = 0; s < 2; ++s) {
            #pragma unroll
            for (int r = 0; r < 4; ++r) {
                uint32_t u = 0;
                #pragma unroll
                for (int e = 0; e < 2; ++e) {
                    const int cch = 32 * s + 8 * h + 2 * r + e;
                    const _Float16 hv = (_Float16)(W2[m * 64 + cch] * sc2);
                    u |= ((uint32_t)__builtin_bit_cast(uint16_t, hv)) << (16 * e);
                }
                outw2[((t * 2 + s) * 64 + lane) * 4 + r] = u;
            }
        }
        float* bo = wpk + (size_t)k * 6144 + 5120;
        #pragma unroll
        for (int r = 0; r < 4; ++r)
            bo[(t * 64 + lane) * 4 + r] = B2[16 * t + 4 * h + r];
        return;
    }

    // ---- per-batch LDS-histogram binning ----
    __shared__ int hist[CPB];
    const int b = blockIdx.x - 2;
    const int tid = threadIdx.x;

    int xs = 0;
    for (int k = 0; k < b; ++k) xs += xcnt[k];
    const int xe = xs + xcnt[b];

    for (int c = tid; c < CPB; c += 1024) hist[c] = 0;
    __syncthreads();

    for (int i = xs + tid; i < xe; i += 1024) {
        const float x = xyz[3 * i], y = xyz[3 * i + 1], z = xyz[3 * i + 2];
        const int cx = min(NXC - 1, max(0, (int)floorf(x * CINV)));
        const int cy = min(NYC - 1, max(0, (int)floorf(y * CINV)));
        const int cz = min(NZC - 1, max(0, (int)floorf(z * CINV)));
        const int cell = (cz * NYC + cy) * NXC + cx;
        const int slot = atomicAdd(&hist[cell], 1);   // LDS atomic
        if (slot < CAP) {
            float4 r; r.x = x; r.y = y; r.z = z; r.w = __int_as_float(i);
            binned4[((size_t)(b * CPB + cell)) * CAP + slot] = r;
        }
    }
    __syncthreads();

    for (int c = tid; c < CPB; c += 1024) cell_cnt[b * CPB + c] = hist[c];
}

// ---------------- fragment gather (issue loads early) ----------------------
struct Frags {
    half8 b0[2], b1[2];
    bool on[2];
    int nt;
};

static __device__ __forceinline__ Frags gather_frags(
    int c_pts, int ntmax, float4 eA, float4 eB,
    const float* __restrict__ feats, int lane)
{
    const int p = lane & 15, h = lane >> 4;
    Frags f;
    f.nt = min((c_pts + 15) >> 4, ntmax);
    #pragma unroll
    for (int pt = 0; pt < 2; ++pt) {
        f.b0[pt] = 0; f.b1[pt] = 0; f.on[pt] = false;
        if (pt < f.nt) {
            const int gp = pt * 16 + p;
            const bool on = gp < c_pts;
            f.on[pt] = on;
            if (on) {
                const float4 e = pt ? eB : eA;
                const int j = (int)(__float_as_uint(e.w) >> 1);
                const float4* f0p = (const float4*)(feats + (size_t)j * 64 + 8 * h);
                const float4* f1p = (const float4*)(feats + (size_t)j * 64 + 32 + 8 * h);
                f.b0[pt] = cvt8(f0p[0], f0p[1]);
                f.b1[pt] = cvt8(f1p[0], f1p[1]);
            }
        }
    }
    return f;
}

// ---------------- per-(query,k) MLP compute (frags pre-gathered) -----------
static __device__ __forceinline__ void mlp_compute(
    const Frags& fr, float4 eA, float4 eB,
    const uint4* __restrict__ wlds, char* __restrict__ hb,
    const float4* __restrict__ bq, float* __restrict__ out_base,
    bool qvalid, int lane)
{
    const int p = lane & 15, h = lane >> 4;

    f32x4 macc[4] = {f32x4(-3e38f), f32x4(-3e38f), f32x4(-3e38f), f32x4(-3e38f)};

    #pragma unroll
    for (int pt = 0; pt < 2; ++pt) {
        if (pt < fr.nt) {
            // rebuild b2 from register-resident record (no memory)
            half8 b2v = 0;
            if (h == 0 && fr.on[pt]) {
                const float4 e = pt ? eB : eA;
                b2v[0] = (_Float16)e.x;
                b2v[1] = (_Float16)e.y;
                b2v[2] = (_Float16)e.z;
                b2v[3] = (_Float16)1.0f;  // bias channel
            }
            f32x4 acc[4] = {f32x4(0.f), f32x4(0.f), f32x4(0.f), f32x4(0.f)};
            #pragma unroll
            for (int t = 0; t < 4; ++t) {
                #pragma unroll
                for (int s = 0; s < 3; ++s) {
                    const half8 a = __builtin_bit_cast(half8, wlds[(t * 3 + s) * 64 + lane]);
                    const half8 bf = (s == 0) ? fr.b0[pt] : ((s == 1) ? fr.b1[pt] : b2v);
                    acc[t] = __builtin_amdgcn_mfma_f32_16x16x32_f16(a, bf, acc[t], 0, 0, 0);
                }
            }
            #pragma unroll
            for (int t = 0; t < 4; ++t) {
                *(uint32_t*)(hb + 144 * p + 32 * t + 8 * h) =
                    pk2(fmaxf(acc[t][0], 0.f), fmaxf(acc[t][1], 0.f));
                *(uint32_t*)(hb + 144 * p + 32 * t + 8 * h + 4) =
                    pk2(fmaxf(acc[t][2], 0.f), fmaxf(acc[t][3], 0.f));
            }
            const half8 g0 = *(const half8*)(hb + 144 * p + 16 * h);
            const half8 g1 = *(const half8*)(hb + 144 * p + 64 + 16 * h);

            f32x4 acc2[4] = {f32x4(0.f), f32x4(0.f), f32x4(0.f), f32x4(0.f)};
            #pragma unroll
            for (int t = 0; t < 4; ++t) {
                #pragma unroll
                for (int s = 0; s < 2; ++s) {
                    const half8 a = __builtin_bit_cast(half8, wlds[768 + (t * 2 + s) * 64 + lane]);
                    const half8 bf = (s == 0) ? g0 : g1;
                    acc2[t] = __builtin_amdgcn_mfma_f32_16x16x32_f16(a, bf, acc2[t], 0, 0, 0);
                }
            }
            #pragma unroll
            for (int t = 0; t < 4; ++t)
                #pragma unroll
                for (int r = 0; r < 4; ++r)
                    if (fr.on[pt]) macc[t][r] = fmaxf(macc[t][r], acc2[t][r]);
        }
    }

    #pragma unroll
    for (int d = 1; d < 16; d <<= 1)
        #pragma unroll
        for (int t = 0; t < 4; ++t)
            #pragma unroll
            for (int r = 0; r < 4; ++r)
                macc[t][r] = fmaxf(macc[t][r], __shfl_xor(macc[t][r], d));

    if (p == 0 && qvalid) {
        float* o = out_base + 4 * h;
        #pragma unroll
        for (int t = 0; t < 4; ++t) {
            const float4 bb = bq[t * 64 + lane];  // = B2[16t+4h+r]
            float4 v;
            v.x = fmaxf(macc[t][0] + bb.x, 0.f);
            v.y = fmaxf(macc[t][1] + bb.y, 0.f);
            v.z = fmaxf(macc[t][2] + bb.z, 0.f);
            v.w = fmaxf(macc[t][3] + bb.w, 0.f);
            *(float4*)(o + 16 * t) = v;
        }
    }
}

// ---------------- K2: fused ball query + MFMA MLP --------------------------
__global__ __launch_bounds__(256, 4) void query_mlp(
    const float* __restrict__ feats,
    const float* __restrict__ new_xyz, const int* __restrict__ ncnt,
    const int* __restrict__ cell_cnt, const float4* __restrict__ binned4,
    const float* __restrict__ wpk, int B, int M,
    float* __restrict__ out)
{
    __shared__ uint4 wlds[1280];               // A-frags for current k (20 KB)
    __shared__ float4 uni[4][176];             // per-wave cand/L4 ∪ hbuf

    const int tid = threadIdx.x;
    const int wave = tid >> 6, lane = tid & 63;
    const int gw = blockIdx.x * 4 + wave;
    const bool qvalid = gw < M;
    const int m = qvalid ? gw : 0;
    const int p = lane & 15;

    // ---- stage k=0 A-frags (hidden under the query phase) ----
    {
        const uint4* ws = (const uint4*)((const uint32_t*)wpk);
        #pragma unroll
        for (int i = 0; i < 5; ++i) wlds[tid + 256 * i] = ws[tid + 256 * i];
    }

    // ---- ball query (both radii, one pass) ----
    int cA = 0, cB = 0;
    float4 ek0, ek1a, ek1b;
    {
        int acc = 0, b = 0;
        for (int k2 = 0; k2 < B; ++k2) { int c = ncnt[k2]; if (m >= acc && m < acc + c) b = k2; acc += c; }
        const float qx = new_xyz[3 * m], qy = new_xyz[3 * m + 1], qz = new_xyz[3 * m + 2];
        const float R0S = 0.64f, R1S = 2.56f;      // exact reference thresholds
        const float PAD = 1.60002f;

        const int lx = max(0, (int)floorf((qx - PAD) * CINV));
        const int hx = min(NXC - 1, (int)floorf((qx + PAD) * CINV));
        const int ly = max(0, (int)floorf((qy - PAD) * CINV));
        const int hy = min(NYC - 1, (int)floorf((qy + PAD) * CINV));
        const int lz = max(0, (int)floorf((qz - PAD) * CINV));
        const int hz = min(NZC - 1, (int)floorf((qz + PAD) * CINV));
        const int wx = hx - lx + 1, wy = hy - ly + 1, wz = hz - lz + 1;
        const int nw = wx * wy * wz;               // <= 27

        int cnt_l = 0, cell_l = 0;
        if (lane < nw) {
            const int wxy = wx * wy;
            const int ldz = lane / wxy;
            const int rem = lane - ldz * wxy;
            const int ldy = rem / wx;
            const int ldx = rem - ldy * wx;
            const int cx = lx + ldx, cy = ly + ldy, cz = lz + ldz;
            const float bx0 = cx * CSZ, by0 = cy * CSZ, bz0 = cz * CSZ;
            const float dx = (qx < bx0) ? (bx0 - qx) : ((qx > bx0 + CSZ) ? (qx - bx0 - CSZ) : 0.f);
            const float dy = (qy < by0) ? (by0 - qy) : ((qy > by0 + CSZ) ? (qy - by0 - CSZ) : 0.f);
            const float dz = (qz < bz0) ? (bz0 - qz) : ((qz > bz0 + CSZ) ? (qz - bz0 - CSZ) : 0.f);
            const float md2 = dx * dx + dy * dy + dz * dz;
            cell_l = b * CPB + (cz * NYC + cy) * NXC + cx;
            if (md2 <= R1S + 1e-3f) cnt_l = min(cell_cnt[cell_l], CAP);
        }

        int incl = cnt_l;
        #pragma unroll
        for (int d = 1; d < 64; d <<= 1) {
            const int v = __shfl_up(incl, d);
            if (lane >= d) incl += v;
        }
        const int excl = incl - cnt_l;
        const int tot = __shfl(incl, 63);

        float4* cd4 = &uni[wave][0];
        float4* L4a = &uni[wave][128];
        float4* L4b = &uni[wave][144];
        const unsigned long long lower = (lane == 0) ? 0ull : (~0ull >> (64 - lane));
        int c = 0, c0n = 0;

        for (int t0 = 0; t0 < tot; t0 += 64) {
            const int t = t0 + lane;
            const bool v = t < tot;
            int lo = 0, hi = 63;
            #pragma unroll
            for (int s = 0; s < 6; ++s) {
                const int mid = (lo + hi) >> 1;
                const int vm = __shfl(incl, mid);
                if (vm > t) hi = mid; else lo = mid + 1;
            }
            const int j = lo & 63;
            const int slot = t - __shfl(excl, j);
            const int cell = __shfl(cell_l, j);
            float d2 = 1e30f;
            float dx = 0.f, dy = 0.f, dzp = 0.f;
            int pid = 0;
            if (v) {
                const float4 e = binned4[(size_t)cell * CAP + slot];
                pid = __float_as_int(e.w);
                dx = e.x - qx; dy = e.y - qy; dzp = e.z - qz;
                // plain fp32, no contraction: matches reference bit-exact
                d2 = __fadd_rn(__fadd_rn(__fmul_rn(dx, dx), __fmul_rn(dy, dy)),
                               __fmul_rn(dzp, dzp));
            }
            const bool keep = v && (d2 < R1S);
            const bool f0 = keep && (d2 < R0S);
            const unsigned long long mk = __ballot(keep);
            const unsigned long long mk0 = __ballot(f0);
            if (keep) {
                const int pos = c + __popcll(mk & lower);
                const uint32_t key = ((uint32_t)pid << 1) | (f0 ? 1u : 0u);
                const float4 rec = make_float4(dx, dy, dzp, __uint_as_float(key));
                if (pos < 128) cd4[pos] = rec;
                if (f0) {
                    const int pos0 = c0n + __popcll(mk0 & lower);
                    if (pos0 < NS0) L4a[pos0] = rec;   // in-scan k0 list
                }
            }
            c += __popcll(mk);
            c0n += __popcll(mk0);
        }

        cA = min(c0n, NS0);
        cB = min(c, NS1);

        if (c > NS1 || c0n > NS0) {
            // rare slow path (~1% of queries): first-nsample by ascending pid.
            const int cc = min(c, 128);
            const float4 fa = (lane < cc) ? cd4[lane]
                                          : make_float4(0, 0, 0, __uint_as_float(0xFFFFFFFFu));
            const float4 fb = (64 + lane < cc) ? cd4[64 + lane]
                                               : make_float4(0, 0, 0, __uint_as_float(0xFFFFFFFFu));
            const uint32_t ka = __float_as_uint(fa.w), kb = __float_as_uint(fb.w);
            int ra = 0, ra0 = 0, rb = 0, rb0 = 0;
            for (int e2 = 0; e2 < cc; e2 += 4) {
                #pragma unroll
                for (int u = 0; u < 4; ++u) {
                    const int ee = e2 + u;
                    if (ee < cc) {
                        const uint32_t ke = __float_as_uint(cd4[ee].w);  // broadcast
                        const int sm_a = (ke < ka), sm_b = (ke < kb), f = (int)(ke & 1u);
                        ra += sm_a; ra0 += sm_a & f;
                        rb += sm_b; rb0 += sm_b & f;
                    }
                }
            }
            if (lane < cc) {
                if ((ka & 1u) && ra0 < NS0) L4a[ra0] = fa;
                if (ra < NS1) L4b[ra] = fa;
            }
            if (64 + lane < cc) {
                if ((kb & 1u) && rb0 < NS0) L4a[rb0] = fb;
                if (rb < NS1) L4b[rb] = fb;
            }
            ek0  = L4a[p];
            ek1a = L4b[p];
            ek1b = L4b[16 + p];
        } else {
            // fast path: ball fits caps -> selected set == all candidates
            ek0  = L4a[p];
            ek1a = cd4[p];
            ek1b = cd4[16 + p];
        }
    }

    // ---- issue BOTH k-groups' feats gathers now (overlapping latencies) ---
    Frags fk0 = gather_frags(cA, 1, ek0, ek0, feats, lane);
    Frags fk1 = gather_frags(cB, 2, ek1a, ek1b, feats, lane);

    __syncthreads();   // k=0 weights staged; gathers drained

    char* hb = (char*)&uni[wave][0];   // aliases cand/L4a (dead)
    mlp_compute(fk0, ek0, ek0, wlds, hb, (const float4*)(wpk + 5120),
                out + (size_t)m * 128, qvalid, lane);

    __syncthreads();   // all waves done reading k=0 weights

    {
        const uint4* ws = (const uint4*)((const uint32_t*)wpk + 6144);
        #pragma unroll
        for (int i = 0; i < 5; ++i) wlds[tid + 256 * i] = ws[tid + 256 * i];
    }
    __syncthreads();   // k=1 weights staged

    mlp_compute(fk1, ek1a, ek1b, wlds, hb, (const float4*)(wpk + 6144 + 5120),
                out + (size_t)m * 128 + 64, qvalid, lane);
}

extern "C" void kernel_launch(void* const* d_in, const int* in_sizes, int n_in,
                              void* d_out, int out_size, void* d_ws, size_t ws_size,
                              hipStream_t stream) {
    const float* xyz     = (const float*)d_in[0];
    const float* feats   = (const float*)d_in[1];
    const float* new_xyz = (const float*)d_in[2];
    const float* w00 = (const float*)d_in[3];
    const float* g00 = (const float*)d_in[4];
    const float* b00 = (const float*)d_in[5];
    const float* w01 = (const float*)d_in[6];
    const float* g01 = (const float*)d_in[7];
    const float* b01 = (const float*)d_in[8];
    const float* w10 = (const float*)d_in[9];
    const float* g10 = (const float*)d_in[10];
    const float* b10 = (const float*)d_in[11];
    const float* w11 = (const float*)d_in[12];
    const float* g11 = (const float*)d_in[13];
    const float* b11 = (const float*)d_in[14];
    const int* xcnt = (const int*)d_in[15];
    const int* ncnt = (const int*)d_in[16];

    const int B = in_sizes[15];
    const int N = in_sizes[0] / 3;
    const int M = in_sizes[2] / 3;
    const int ncells = B * CPB;
    const int ncells_pad = (ncells + 3) & ~3;

    // workspace layout (u32 units; every section a multiple of 4 u32s)
    uint32_t* w32 = (uint32_t*)d_ws;
    float* wpk      = (float*)w32;                     // 12288
    int* cell_cnt   = (int*)(w32 + 12288);             // ncells_pad
    float4* binned4 = (float4*)(cell_cnt + ncells_pad);// ncells*CAP float4

    prep_bin<<<2 + B, 1024, 0, stream>>>(
        xyz, xcnt, N,
        w00, g00, b00, w01, g01, b01, w10, g10, b10, w11, g11, b11,
        wpk, cell_cnt, binned4);
    query_mlp<<<(M + 3) / 4, 256, 0, stream>>>(feats, new_xyz, ncnt,
                                               cell_cnt, binned4, wpk, B, M,
                                               (float*)d_out);
}

// Round 17
// 31.267 us; speedup vs baseline: 1.0487x; 1.0487x over previous
//
#include <hip/hip_runtime.h>
#include <hip/hip_bf16.h>
#include <stdint.h>

// VoxelSetAbstraction: ball query + group + shared MLP (2 layers) + maxpool.
// Round 17 (FINAL): revert to R15 — the proven best (31.6us). R16's early
// k=1 gather regressed (register pressure across barriers > latency hidden).
//   K1 prep_bin: blocks 0-1 pack scaled weights; blocks 2..B+1 LDS-histogram
//      binning (no global zeroing, no global atomics).
//   K2 query_mlp: per-wave query + MFMA MLP (A-frags in block LDS), fast-path
//      selection (rank loop only on cap overflow, ~1% of queries).
//
// Fixed instance: RADII=(0.8,1.6), NSAMPLES=(16,32), IN_C=64, cin=67,
// BOX=(40,40,4), B=2, N=16384, M=4096.
// Radius constants: reference computes r*r in f64 then weak-casts to f32:
// f32(0.64) / f32(2.56) == literals 0.64f / 2.56f (NOT 0.8f*0.8f, 1 ulp off).

#define NS0 16
#define NS1 32
#define NXC 25
#define NYC 25
#define NZC 3
#define CPB (NXC * NYC * NZC)   // 1875 cells per batch
#define CINV 0.625f             // 1/1.6, exact in fp32
#define CSZ 1.6f
#define CAP 48                  // max points/cell (Poisson lambda~5.2 -> safe)

typedef _Float16 half8 __attribute__((ext_vector_type(8)));
typedef float f32x4 __attribute__((ext_vector_type(4)));

static __device__ __forceinline__ half8 cvt8(float4 a, float4 b) {
    half8 r;
    r[0] = (_Float16)a.x; r[1] = (_Float16)a.y; r[2] = (_Float16)a.z; r[3] = (_Float16)a.w;
    r[4] = (_Float16)b.x; r[5] = (_Float16)b.y; r[6] = (_Float16)b.z; r[7] = (_Float16)b.w;
    return r;
}
static __device__ __forceinline__ uint32_t pk2(float x, float y) {
    const _Float16 a = (_Float16)x, c = (_Float16)y;
    return (uint32_t)__builtin_bit_cast(uint16_t, a) |
           ((uint32_t)__builtin_bit_cast(uint16_t, c) << 16);
}

// ---------------- K1: pack weights (blocks 0-1) || bin (blocks 2..B+1) -----
__global__ __launch_bounds__(1024) void prep_bin(
    const float* __restrict__ xyz, const int* __restrict__ xcnt, int N,
    const float* __restrict__ w00, const float* __restrict__ g00, const float* __restrict__ b00,
    const float* __restrict__ w01, const float* __restrict__ g01, const float* __restrict__ b01,
    const float* __restrict__ w10, const float* __restrict__ g10, const float* __restrict__ b10,
    const float* __restrict__ w11, const float* __restrict__ g11, const float* __restrict__ b11,
    float* __restrict__ wpk, int* __restrict__ cell_cnt,
    float4* __restrict__ binned4)
{
    if (blockIdx.x < 2) {
        // ---- weight packing (256 active threads; done ONCE, not per-block)
        const int k = blockIdx.x;
        const int tid = threadIdx.x;
        if (tid >= 256) return;
        const int lane = tid & 63, t = tid >> 6;
        const int p = lane & 15, h = lane >> 4;
        const float* W1 = k ? w10 : w00; const float* G1 = k ? g10 : g00; const float* B1 = k ? b10 : b00;
        const float* W2 = k ? w11 : w01; const float* G2 = k ? g11 : g01; const float* B2 = k ? b11 : b01;
        const float inv = 1.0f / sqrtf(1.0f + 1e-3f);

        uint32_t* outw = (uint32_t*)wpk + (size_t)k * 6144;
        const int m = 16 * t + p;
        const float sc1 = G1[m] * inv;
        #pragma unroll
        for (int s = 0; s < 3; ++s) {
            #pragma unroll
            for (int r = 0; r < 4; ++r) {
                uint32_t u = 0;
                #pragma unroll
                for (int e = 0; e < 2; ++e) {
                    const int cpad = 32 * s + 8 * h + 2 * r + e;
                    float val = 0.f;
                    if (cpad < 64)       val = W1[m * 67 + 3 + cpad] * sc1;
                    else if (cpad < 67)  val = W1[m * 67 + (cpad - 64)] * sc1;
                    else if (cpad == 67) val = B1[m];
                    const _Float16 hv = (_Float16)val;
                    u |= ((uint32_t)__builtin_bit_cast(uint16_t, hv)) << (16 * e);
                }
                outw[((t * 3 + s) * 64 + lane) * 4 + r] = u;
            }
        }
        const float sc2 = G2[m] * inv;
        uint32_t* outw2 = outw + 3072;
        #pragma unroll
        for (int s = 0; s < 2; ++s) {
            #pragma unroll
            for (int r = 0; r < 4; ++r) {
                uint32_t u = 0;
                #pragma unroll
                for (int e = 0; e < 2; ++e) {
                    const int cch = 32 * s + 8 * h + 2 * r + e;
                    const _Float16 hv = (_Float16)(W2[m * 64 + cch] * sc2);
                    u |= ((uint32_t)__builtin_bit_cast(uint16_t, hv)) << (16 * e);
                }
                outw2[((t * 2 + s) * 64 + lane) * 4 + r] = u;
            }
        }
        float* bo = wpk + (size_t)k * 6144 + 5120;
        #pragma unroll
        for (int r = 0; r < 4; ++r)
            bo[(t * 64 + lane) * 4 + r] = B2[16 * t + 4 * h + r];
        return;
    }

    // ---- per-batch LDS-histogram binning ----
    __shared__ int hist[CPB];
    const int b = blockIdx.x - 2;
    const int tid = threadIdx.x;

    int xs = 0;
    for (int k = 0; k < b; ++k) xs += xcnt[k];
    const int xe = xs + xcnt[b];

    for (int c = tid; c < CPB; c += 1024) hist[c] = 0;
    __syncthreads();

    for (int i = xs + tid; i < xe; i += 1024) {
        const float x = xyz[3 * i], y = xyz[3 * i + 1], z = xyz[3 * i + 2];
        const int cx = min(NXC - 1, max(0, (int)floorf(x * CINV)));
        const int cy = min(NYC - 1, max(0, (int)floorf(y * CINV)));
        const int cz = min(NZC - 1, max(0, (int)floorf(z * CINV)));
        const int cell = (cz * NYC + cy) * NXC + cx;
        const int slot = atomicAdd(&hist[cell], 1);   // LDS atomic
        if (slot < CAP) {
            float4 r; r.x = x; r.y = y; r.z = z; r.w = __int_as_float(i);
            binned4[((size_t)(b * CPB + cell)) * CAP + slot] = r;
        }
    }
    __syncthreads();

    for (int c = tid; c < CPB; c += 1024) cell_cnt[b * CPB + c] = hist[c];
}

// ---------------- per-(query,k) MLP; A-frags in LDS; e-records in regs -----
static __device__ __forceinline__ void mlp_one(
    int c_pts, int ntmax, float4 eA, float4 eB,
    const uint4* __restrict__ wlds, char* __restrict__ hb,
    const float* __restrict__ feats, const float4* __restrict__ bq,
    float* __restrict__ out_base, bool qvalid, int lane)
{
    const int p = lane & 15, h = lane >> 4;
    const int nt = min((c_pts + 15) >> 4, ntmax);

    f32x4 macc[4] = {f32x4(-3e38f), f32x4(-3e38f), f32x4(-3e38f), f32x4(-3e38f)};

    half8 b0a[2], b1a[2], b2a[2];
    bool ona[2];
    #pragma unroll
    for (int pt = 0; pt < 2; ++pt) {
        b0a[pt] = 0; b1a[pt] = 0; b2a[pt] = 0; ona[pt] = false;
        if (pt < nt) {
            const int gp = pt * 16 + p;
            const bool on = gp < c_pts;
            ona[pt] = on;
            if (on) {
                const float4 e = pt ? eB : eA;
                const int j = (int)(__float_as_uint(e.w) >> 1);
                const float4* f0p = (const float4*)(feats + (size_t)j * 64 + 8 * h);
                const float4* f1p = (const float4*)(feats + (size_t)j * 64 + 32 + 8 * h);
                b0a[pt] = cvt8(f0p[0], f0p[1]);
                b1a[pt] = cvt8(f1p[0], f1p[1]);
                if (h == 0) {
                    half8 b2 = 0;
                    b2[0] = (_Float16)e.x;
                    b2[1] = (_Float16)e.y;
                    b2[2] = (_Float16)e.z;
                    b2[3] = (_Float16)1.0f;  // bias channel
                    b2a[pt] = b2;
                }
            }
        }
    }

    #pragma unroll
    for (int pt = 0; pt < 2; ++pt) {
        if (pt < nt) {
            f32x4 acc[4] = {f32x4(0.f), f32x4(0.f), f32x4(0.f), f32x4(0.f)};
            #pragma unroll
            for (int t = 0; t < 4; ++t) {
                #pragma unroll
                for (int s = 0; s < 3; ++s) {
                    const half8 a = __builtin_bit_cast(half8, wlds[(t * 3 + s) * 64 + lane]);
                    const half8 bf = (s == 0) ? b0a[pt] : ((s == 1) ? b1a[pt] : b2a[pt]);
                    acc[t] = __builtin_amdgcn_mfma_f32_16x16x32_f16(a, bf, acc[t], 0, 0, 0);
                }
            }
            #pragma unroll
            for (int t = 0; t < 4; ++t) {
                *(uint32_t*)(hb + 144 * p + 32 * t + 8 * h) =
                    pk2(fmaxf(acc[t][0], 0.f), fmaxf(acc[t][1], 0.f));
                *(uint32_t*)(hb + 144 * p + 32 * t + 8 * h + 4) =
                    pk2(fmaxf(acc[t][2], 0.f), fmaxf(acc[t][3], 0.f));
            }
            const half8 g0 = *(const half8*)(hb + 144 * p + 16 * h);
            const half8 g1 = *(const half8*)(hb + 144 * p + 64 + 16 * h);

            f32x4 acc2[4] = {f32x4(0.f), f32x4(0.f), f32x4(0.f), f32x4(0.f)};
            #pragma unroll
            for (int t = 0; t < 4; ++t) {
                #pragma unroll
                for (int s = 0; s < 2; ++s) {
                    const half8 a = __builtin_bit_cast(half8, wlds[768 + (t * 2 + s) * 64 + lane]);
                    const half8 bf = (s == 0) ? g0 : g1;
                    acc2[t] = __builtin_amdgcn_mfma_f32_16x16x32_f16(a, bf, acc2[t], 0, 0, 0);
                }
            }
            #pragma unroll
            for (int t = 0; t < 4; ++t)
                #pragma unroll
                for (int r = 0; r < 4; ++r)
                    if (ona[pt]) macc[t][r] = fmaxf(macc[t][r], acc2[t][r]);
        }
    }

    #pragma unroll
    for (int d = 1; d < 16; d <<= 1)
        #pragma unroll
        for (int t = 0; t < 4; ++t)
            #pragma unroll
            for (int r = 0; r < 4; ++r)
                macc[t][r] = fmaxf(macc[t][r], __shfl_xor(macc[t][r], d));

    if (p == 0 && qvalid) {
        float* o = out_base + 4 * h;
        #pragma unroll
        for (int t = 0; t < 4; ++t) {
            const float4 bb = bq[t * 64 + lane];  // = B2[16t+4h+r]
            float4 v;
            v.x = fmaxf(macc[t][0] + bb.x, 0.f);
            v.y = fmaxf(macc[t][1] + bb.y, 0.f);
            v.z = fmaxf(macc[t][2] + bb.z, 0.f);
            v.w = fmaxf(macc[t][3] + bb.w, 0.f);
            *(float4*)(o + 16 * t) = v;
        }
    }
}

// ---------------- K2: fused ball query + MFMA MLP --------------------------
__global__ __launch_bounds__(256, 4) void query_mlp(
    const float* __restrict__ feats,
    const float* __restrict__ new_xyz, const int* __restrict__ ncnt,
    const int* __restrict__ cell_cnt, const float4* __restrict__ binned4,
    const float* __restrict__ wpk, int B, int M,
    float* __restrict__ out)
{
    __shared__ uint4 wlds[1280];               // A-frags for current k (20 KB)
    __shared__ float4 uni[4][176];             // per-wave cand/L4 ∪ hbuf

    const int tid = threadIdx.x;
    const int wave = tid >> 6, lane = tid & 63;
    const int gw = blockIdx.x * 4 + wave;
    const bool qvalid = gw < M;
    const int m = qvalid ? gw : 0;
    const int p = lane & 15;

    // ---- stage k=0 A-frags (hidden under the query phase) ----
    {
        const uint4* ws = (const uint4*)((const uint32_t*)wpk);
        #pragma unroll
        for (int i = 0; i < 5; ++i) wlds[tid + 256 * i] = ws[tid + 256 * i];
    }

    // ---- ball query (both radii, one pass) ----
    int cA = 0, cB = 0;
    float4 ek0, ek1a, ek1b;
    {
        int acc = 0, b = 0;
        for (int k2 = 0; k2 < B; ++k2) { int c = ncnt[k2]; if (m >= acc && m < acc + c) b = k2; acc += c; }
        const float qx = new_xyz[3 * m], qy = new_xyz[3 * m + 1], qz = new_xyz[3 * m + 2];
        const float R0S = 0.64f, R1S = 2.56f;      // exact reference thresholds
        const float PAD = 1.60002f;

        const int lx = max(0, (int)floorf((qx - PAD) * CINV));
        const int hx = min(NXC - 1, (int)floorf((qx + PAD) * CINV));
        const int ly = max(0, (int)floorf((qy - PAD) * CINV));
        const int hy = min(NYC - 1, (int)floorf((qy + PAD) * CINV));
        const int lz = max(0, (int)floorf((qz - PAD) * CINV));
        const int hz = min(NZC - 1, (int)floorf((qz + PAD) * CINV));
        const int wx = hx - lx + 1, wy = hy - ly + 1, wz = hz - lz + 1;
        const int nw = wx * wy * wz;               // <= 27

        int cnt_l = 0, cell_l = 0;
        if (lane < nw) {
            const int wxy = wx * wy;
            const int ldz = lane / wxy;
            const int rem = lane - ldz * wxy;
            const int ldy = rem / wx;
            const int ldx = rem - ldy * wx;
            const int cx = lx + ldx, cy = ly + ldy, cz = lz + ldz;
            const float bx0 = cx * CSZ, by0 = cy * CSZ, bz0 = cz * CSZ;
            const float dx = (qx < bx0) ? (bx0 - qx) : ((qx > bx0 + CSZ) ? (qx - bx0 - CSZ) : 0.f);
            const float dy = (qy < by0) ? (by0 - qy) : ((qy > by0 + CSZ) ? (qy - by0 - CSZ) : 0.f);
            const float dz = (qz < bz0) ? (bz0 - qz) : ((qz > bz0 + CSZ) ? (qz - bz0 - CSZ) : 0.f);
            const float md2 = dx * dx + dy * dy + dz * dz;
            cell_l = b * CPB + (cz * NYC + cy) * NXC + cx;
            if (md2 <= R1S + 1e-3f) cnt_l = min(cell_cnt[cell_l], CAP);
        }

        int incl = cnt_l;
        #pragma unroll
        for (int d = 1; d < 64; d <<= 1) {
            const int v = __shfl_up(incl, d);
            if (lane >= d) incl += v;
        }
        const int excl = incl - cnt_l;
        const int tot = __shfl(incl, 63);

        float4* cd4 = &uni[wave][0];
        float4* L4a = &uni[wave][128];
        float4* L4b = &uni[wave][144];
        const unsigned long long lower = (lane == 0) ? 0ull : (~0ull >> (64 - lane));
        int c = 0, c0n = 0;

        for (int t0 = 0; t0 < tot; t0 += 64) {
            const int t = t0 + lane;
            const bool v = t < tot;
            int lo = 0, hi = 63;
            #pragma unroll
            for (int s = 0; s < 6; ++s) {
                const int mid = (lo + hi) >> 1;
                const int vm = __shfl(incl, mid);
                if (vm > t) hi = mid; else lo = mid + 1;
            }
            const int j = lo & 63;
            const int slot = t - __shfl(excl, j);
            const int cell = __shfl(cell_l, j);
            float d2 = 1e30f;
            float dx = 0.f, dy = 0.f, dzp = 0.f;
            int pid = 0;
            if (v) {
                const float4 e = binned4[(size_t)cell * CAP + slot];
                pid = __float_as_int(e.w);
                dx = e.x - qx; dy = e.y - qy; dzp = e.z - qz;
                // plain fp32, no contraction: matches reference bit-exact
                d2 = __fadd_rn(__fadd_rn(__fmul_rn(dx, dx), __fmul_rn(dy, dy)),
                               __fmul_rn(dzp, dzp));
            }
            const bool keep = v && (d2 < R1S);
            const bool f0 = keep && (d2 < R0S);
            const unsigned long long mk = __ballot(keep);
            const unsigned long long mk0 = __ballot(f0);
            if (keep) {
                const int pos = c + __popcll(mk & lower);
                const uint32_t key = ((uint32_t)pid << 1) | (f0 ? 1u : 0u);
                const float4 rec = make_float4(dx, dy, dzp, __uint_as_float(key));
                if (pos < 128) cd4[pos] = rec;
                if (f0) {
                    const int pos0 = c0n + __popcll(mk0 & lower);
                    if (pos0 < NS0) L4a[pos0] = rec;   // in-scan k0 list
                }
            }
            c += __popcll(mk);
            c0n += __popcll(mk0);
        }

        cA = min(c0n, NS0);
        cB = min(c, NS1);

        if (c > NS1 || c0n > NS0) {
            // rare slow path (~1% of queries): first-nsample by ascending pid.
            // Rank loop rewrites every needed list position (ranks 0..NSk-1
            // each occur exactly once), so in-scan entries are overwritten.
            const int cc = min(c, 128);
            const float4 fa = (lane < cc) ? cd4[lane]
                                          : make_float4(0, 0, 0, __uint_as_float(0xFFFFFFFFu));
            const float4 fb = (64 + lane < cc) ? cd4[64 + lane]
                                               : make_float4(0, 0, 0, __uint_as_float(0xFFFFFFFFu));
            const uint32_t ka = __float_as_uint(fa.w), kb = __float_as_uint(fb.w);
            int ra = 0, ra0 = 0, rb = 0, rb0 = 0;
            for (int e2 = 0; e2 < cc; e2 += 4) {
                #pragma unroll
                for (int u = 0; u < 4; ++u) {
                    const int ee = e2 + u;
                    if (ee < cc) {
                        const uint32_t ke = __float_as_uint(cd4[ee].w);  // broadcast
                        const int sm_a = (ke < ka), sm_b = (ke < kb), f = (int)(ke & 1u);
                        ra += sm_a; ra0 += sm_a & f;
                        rb += sm_b; rb0 += sm_b & f;
                    }
                }
            }
            if (lane < cc) {
                if ((ka & 1u) && ra0 < NS0) L4a[ra0] = fa;
                if (ra < NS1) L4b[ra] = fa;
            }
            if (64 + lane < cc) {
                if ((kb & 1u) && rb0 < NS0) L4a[rb0] = fb;
                if (rb < NS1) L4b[rb] = fb;
            }
            ek0  = L4a[p];
            ek1a = L4b[p];
            ek1b = L4b[16 + p];
        } else {
            // fast path: ball fits caps -> selected set == all candidates;
            // scan order is fine under max-pool.
            ek0  = L4a[p];
            ek1a = cd4[p];
            ek1b = cd4[16 + p];
        }
    }

    __syncthreads();   // k=0 weights staged

    char* hb = (char*)&uni[wave][0];   // aliases cand/L4a (dead)
    mlp_one(cA, 1, ek0, ek0, wlds, hb, feats,
            (const float4*)(wpk + 5120), out + (size_t)m * 128, qvalid, lane);

    __syncthreads();   // all waves done reading k=0 weights

    {
        const uint4* ws = (const uint4*)((const uint32_t*)wpk + 6144);
        #pragma unroll
        for (int i = 0; i < 5; ++i) wlds[tid + 256 * i] = ws[tid + 256 * i];
    }
    __syncthreads();   // k=1 weights staged

    mlp_one(cB, 2, ek1a, ek1b, wlds, hb, feats,
            (const float4*)(wpk + 6144 + 5120), out + (size_t)m * 128 + 64,
            qvalid, lane);
}

extern "C" void kernel_launch(void* const* d_in, const int* in_sizes, int n_in,
                              void* d_out, int out_size, void* d_ws, size_t ws_size,
                              hipStream_t stream) {
    const float* xyz     = (const float*)d_in[0];
    const float* feats   = (const float*)d_in[1];
    const float* new_xyz = (const float*)d_in[2];
    const float* w00 = (const float*)d_in[3];
    const float* g00 = (const float*)d_in[4];
    const float* b00 = (const float*)d_in[5];
    const float* w01 = (const float*)d_in[6];
    const float* g01 = (const float*)d_in[7];
    const float* b01 = (const float*)d_in[8];
    const float* w10 = (const float*)d_in[9];
    const float* g10 = (const float*)d_in[10];
    const float* b10 = (const float*)d_in[11];
    const float* w11 = (const float*)d_in[12];
    const float* g11 = (const float*)d_in[13];
    const float* b11 = (const float*)d_in[14];
    const int* xcnt = (const int*)d_in[15];
    const int* ncnt = (const int*)d_in[16];

    const int B = in_sizes[15];
    const int N = in_sizes[0] / 3;
    const int M = in_sizes[2] / 3;
    const int ncells = B * CPB;
    const int ncells_pad = (ncells + 3) & ~3;

    // workspace layout (u32 units; every section a multiple of 4 u32s)
    uint32_t* w32 = (uint32_t*)d_ws;
    float* wpk      = (float*)w32;                     // 12288
    int* cell_cnt   = (int*)(w32 + 12288);             // ncells_pad
    float4* binned4 = (float4*)(cell_cnt + ncells_pad);// ncells*CAP float4

    prep_bin<<<2 + B, 1024, 0, stream>>>(
        xyz, xcnt, N,
        w00, g00, b00, w01, g01, b01, w10, g10, b10, w11, g11, b11,
        wpk, cell_cnt, binned4);
    query_mlp<<<(M + 3) / 4, 256, 0, stream>>>(feats, new_xyz, ncnt,
                                               cell_cnt, binned4, wpk, B, M,
                                               (float*)d_out);
}